// Round 4
// baseline (165.488 us; speedup 1.0000x reference)
//
#include <hip/hip_runtime.h>

// LTAE2d tiny, folded: score[h,pix,l] = 0.5*( sum_g inv_g*(d_g[h][l] - mu_g*U[h][g])
//                                             + wb[h] + s0[h] + pterm[h][b][l] )
// u[h][c] = (Q[h]·Wk_h)·conv_w · gn_w[c].
// k01: blocks 0..511 = GN stats; block 512 = all small precompute (hidden under stats).
// k2: scores (float4 px, b128 u-broadcast, g-loop unroll 2). k3: softmax over L=30.

#define EPSV 1e-5f

// ws float offsets
#define WS_U    0          // u[c][h]        128*16
#define WS_UU   2048       // U[g][h]        16*16
#define WS_P2   2304       // P2[b*30+l][h]  120*16
#define WS_FLAG 4224       // flag[b*30+l]   120
#define WS_QT   4352       // qt[h][m]       16*256
#define WS_WT   8448       // wt[h][c]       16*128
#define WS_INV  10496      // inv[g][pix]    16*16384
#define WS_MUI  272640     // mu*inv[g][pix] 16*16384

// ---- k01: stats (blocks 0..511) + precompute (block 512) ----
__global__ void __launch_bounds__(256) k01(const float* __restrict__ Q,
                                           const float* __restrict__ Wk,
                                           const float* __restrict__ conv_w,
                                           const float* __restrict__ gn_w,
                                           const float* __restrict__ conv_b,
                                           const float* __restrict__ gn_b,
                                           const float* __restrict__ bk,
                                           const int* __restrict__ bpos,
                                           const unsigned char* __restrict__ pmask,
                                           const float* __restrict__ x,
                                           float* __restrict__ ws) {
    __shared__ float sc[16];
    __shared__ float qsv[256];
    __shared__ float rden[16];
    int t = threadIdx.x;
    int bx = blockIdx.x;
    if (bx == 512) {
        // ---- precompute path (one block; hidden under the 512 stats blocks) ----
        // stage A: qt[h][m] = sum_d Q[h][d]*Wk[h*4+d][m]
        for (int i = t; i < 4096; i += 256) {
            int h = i >> 8, m = i & 255;
            float s = 0.f;
            #pragma unroll
            for (int d = 0; d < 4; ++d) s += Q[h*4+d] * Wk[(h*4+d)*256 + m];
            ws[WS_QT + h*256 + m] = s;
        }
        __syncthreads();
        // stage B: wt[h][c] = qt[h]·conv_w[:,c]; u[c][h] = wt*gn_w[c]
        for (int i = t; i < 2048; i += 256) {
            int h = i >> 7, c = i & 127;
            const float* qt = ws + WS_QT + h*256;
            float s = 0.f;
            #pragma unroll 32
            for (int m = 0; m < 256; ++m) s += qt[m] * conv_w[m*128 + c];
            ws[WS_WT + h*128 + c] = s;
            ws[WS_U  + c*16  + h] = s * gn_w[c];
        }
        __syncthreads();
        // stage C
        {
            int h = t >> 4, g = t & 15;
            float s = 0.f;
            #pragma unroll
            for (int cc = 0; cc < 8; ++cc) s += ws[WS_U + (g*8+cc)*16 + h];
            ws[WS_UU + g*16 + h] = s;
            float q = 0.f;
            #pragma unroll
            for (int r = 0; r < 16; ++r) q += ws[WS_QT + h*256 + r*16 + g];
            qsv[h*16 + g] = q;
        }
        if (t < 16) {
            int h = t;
            float wb = 0.f;
            #pragma unroll 16
            for (int c = 0; c < 128; ++c) wb += ws[WS_WT + h*128 + c] * gn_b[c];
            float s0 = 0.f;
            #pragma unroll 16
            for (int m = 0; m < 256; ++m) s0 += ws[WS_QT + h*256 + m] * conv_b[m];
            #pragma unroll
            for (int d = 0; d < 4; ++d) s0 += Q[h*4+d] * bk[h*4+d];
            sc[h] = wb + s0;
            rden[t] = powf(1000.0f, -((float)(t >> 1)) * 0.125f);
        }
        if (t < 120) ws[WS_FLAG + t] = pmask[t] ? 1.f : 0.f;
        __syncthreads();
        for (int idx = t; idx < 1920; idx += 256) {
            int h = idx / 120, r = idx - h*120;     // r = b*30+l
            float pos = (float)bpos[r];
            float pt = 0.f;
            #pragma unroll
            for (int p = 0; p < 16; ++p) {
                float tab = pos * rden[p];
                float v = (p & 1) ? cosf(tab) : sinf(tab);
                pt += v * qsv[h*16 + p];
            }
            ws[WS_P2 + r*16 + h] = pt + sc[h];
        }
        return;
    }
    // ---- stats path: per (pixel,group) mean & rsqrt over 8 c x 30 l ----
    int g = bx >> 5;
    int pq = (bx & 31)*256 + t;
    int pix0 = pq*2;
    int b = pix0 >> 12, pij = pix0 & 4095;
    const float2* xp = (const float2*)(x + (b*30*128 + g*8)*4096 + pij);
    float sx = 0.f, sy = 0.f, ssx = 0.f, ssy = 0.f;
    for (int l = 0; l < 30; ++l) {
        const float2* xl = xp + l*128*2048;
        #pragma unroll
        for (int c = 0; c < 8; ++c) {
            float2 v = xl[c*2048];
            sx += v.x; sy += v.y;
            ssx += v.x*v.x; ssy += v.y*v.y;
        }
    }
    float mux = sx*(1.f/240.f), muy = sy*(1.f/240.f);
    float ivx = rsqrtf(ssx*(1.f/240.f) - mux*mux + EPSV);
    float ivy = rsqrtf(ssy*(1.f/240.f) - muy*muy + EPSV);
    *(float2*)(ws + WS_INV + g*16384 + pix0) = make_float2(ivx, ivy);
    *(float2*)(ws + WS_MUI + g*16384 + pix0) = make_float2(mux*ivx, muy*ivy);
}

#define FMA4(A, S, V) { (A).x += (S)*(V).x; (A).y += (S)*(V).y; (A).z += (S)*(V).z; (A).w += (S)*(V).w; }
#define NMA4(A, S, V) { (A).x -= (S)*(V).x; (A).y -= (S)*(V).y; (A).z -= (S)*(V).z; (A).w -= (S)*(V).w; }

// ---- k2: raw scores, 4 pixels/thread, g-loop unroll 2 ----
__global__ void __launch_bounds__(256) k2(const float* __restrict__ x,
                                          const float* __restrict__ ws,
                                          float* __restrict__ out) {
    __shared__ float su[2048];   // u[c][h], h contiguous
    __shared__ float sU[256];    // U[g][h], h contiguous
    __shared__ float sP2[16];
    __shared__ float sflag;
    int t = threadIdx.x;
    int bx = blockIdx.x;                 // 480 blocks: pb2 = bx/30, l = bx%30
    int pb2 = bx / 30, l = bx - pb2*30;
    int pixbase = pb2 * 1024;            // block-uniform
    int b = pixbase >> 12;
    int pijb = pixbase & 4095;
    int bl = b*30 + l;
    int pij = pijb + t*4;
    int pix0 = pixbase + t*4;

    for (int i = t; i < 512; i += 256)
        *(float4*)(su + i*4) = *(const float4*)(ws + WS_U + i*4);
    sU[t] = ws[WS_UU + t];
    if (t < 16) sP2[t] = ws[WS_P2 + bl*16 + t];
    if (t == 0) sflag = ws[WS_FLAG + bl];
    __syncthreads();

    float4 acc[16];
    #pragma unroll
    for (int h = 0; h < 16; ++h) acc[h] = make_float4(0.f, 0.f, 0.f, 0.f);
    const float* xbase = x + (bl*128)*4096 + pij;
    #pragma unroll 2
    for (int g = 0; g < 16; ++g) {
        float4 inv = *(const float4*)(ws + WS_INV + g*16384 + pix0);
        float4 mui = *(const float4*)(ws + WS_MUI + g*16384 + pix0);
        const float* us = su + g*128;
        #pragma unroll
        for (int q = 0; q < 4; ++q) {
            float4 Ug = *(const float4*)(sU + g*16 + q*4);
            NMA4(acc[q*4+0], Ug.x, mui); NMA4(acc[q*4+1], Ug.y, mui);
            NMA4(acc[q*4+2], Ug.z, mui); NMA4(acc[q*4+3], Ug.w, mui);
        }
        const float* xg = xbase + g*8*4096;
        #pragma unroll
        for (int cc = 0; cc < 8; ++cc) {
            float4 v = *(const float4*)(xg + cc*4096);
            float4 xs;
            xs.x = v.x*inv.x; xs.y = v.y*inv.y; xs.z = v.z*inv.z; xs.w = v.w*inv.w;
            #pragma unroll
            for (int q = 0; q < 4; ++q) {
                float4 uq = *(const float4*)(us + cc*16 + q*4);  // ds_read_b128 broadcast
                FMA4(acc[q*4+0], uq.x, xs); FMA4(acc[q*4+1], uq.y, xs);
                FMA4(acc[q*4+2], uq.z, xs); FMA4(acc[q*4+3], uq.w, xs);
            }
        }
    }
    bool msk = (sflag != 0.f);
    #pragma unroll
    for (int h = 0; h < 16; ++h) {
        float p2 = sP2[h];
        float4 sv;
        sv.x = 0.5f*(acc[h].x + p2); sv.y = 0.5f*(acc[h].y + p2);
        sv.z = 0.5f*(acc[h].z + p2); sv.w = 0.5f*(acc[h].w + p2);
        if (msk) sv = make_float4(-1000.f, -1000.f, -1000.f, -1000.f);
        *(float4*)(out + ((h*4 + b)*30 + l)*4096 + pij) = sv;
    }
}

// ---- k3: softmax over l, 2 pixels/thread, 512 blocks for occupancy ----
__global__ void __launch_bounds__(256) k3(float* __restrict__ out) {
    int idx = blockIdx.x*256 + threadIdx.x;   // 131072 threads
    int hb = idx >> 11;                       // 64 (h*4+b) slabs
    int pij = (idx & 2047)*2;
    float* p = out + hb*30*4096 + pij;
    float2 v[30];
    float m0 = -1e30f, m1 = -1e30f;
    #pragma unroll
    for (int l = 0; l < 30; ++l) {
        v[l] = *(const float2*)(p + l*4096);
        m0 = fmaxf(m0, v[l].x); m1 = fmaxf(m1, v[l].y);
    }
    float s0 = 0.f, s1 = 0.f;
    #pragma unroll
    for (int l = 0; l < 30; ++l) {
        v[l].x = __expf(v[l].x - m0); s0 += v[l].x;
        v[l].y = __expf(v[l].y - m1); s1 += v[l].y;
    }
    float r0 = 1.f/s0, r1 = 1.f/s1;
    #pragma unroll
    for (int l = 0; l < 30; ++l) {
        *(float2*)(p + l*4096) = make_float2(v[l].x*r0, v[l].y*r1);
    }
}

extern "C" void kernel_launch(void* const* d_in, const int* in_sizes, int n_in,
                              void* d_out, int out_size, void* d_ws, size_t ws_size,
                              hipStream_t stream) {
    const float* x      = (const float*)d_in[0];
    const float* gn_w   = (const float*)d_in[1];
    const float* gn_b   = (const float*)d_in[2];
    const float* conv_w = (const float*)d_in[3];
    const float* conv_b = (const float*)d_in[4];
    const float* Q      = (const float*)d_in[5];
    const float* Wk     = (const float*)d_in[6];
    const float* bk     = (const float*)d_in[7];
    const int*   bpos   = (const int*)d_in[8];
    const unsigned char* pmask = (const unsigned char*)d_in[9];
    float* ws  = (float*)d_ws;
    float* out = (float*)d_out;

    hipLaunchKernelGGL(k01, dim3(513), dim3(256), 0, stream,
                       Q, Wk, conv_w, gn_w, conv_b, gn_b, bk, bpos, pmask, x, ws);
    hipLaunchKernelGGL(k2,  dim3(480), dim3(256), 0, stream, x, ws, out);
    hipLaunchKernelGGL(k3,  dim3(512), dim3(256), 0, stream, out);
}

// Round 5
// 157.967 us; speedup vs baseline: 1.0476x; 1.0476x over previous
//
#include <hip/hip_runtime.h>

// LTAE2d tiny, folded: score[h,pix,l] = 0.5*( sum_g inv_g*(d_g[h][l] - mu_g*U[h][g])
//                                             + wb[h] + s0[h] + pterm[h][b][l] )
// k1 : blocks 0..959 = GN partial stats (contiguous 128KB streams, partials -> d_out scratch)
//      block 960     = small precompute (u, U, P2, flags), hidden under stats
// k1r: reduce 15 l-chunk partials -> inv/mui in ws
// k2 : scores (float4 px, b128 u-broadcast)   k3: softmax over L=30

#define EPSV 1e-5f

// ws float offsets
#define WS_U    0          // u[c][h]        128*16
#define WS_UU   2048       // U[g][h]        16*16
#define WS_P2   2304       // P2[b*30+l][h]  120*16
#define WS_FLAG 4224       // flag[b*30+l]   120
#define WS_QT   4352       // qt[h][m]       16*256
#define WS_WT   8448       // wt[h][c]       16*128
#define WS_INV  10496      // inv[g][pix]    16*16384
#define WS_MUI  272640     // mu*inv[g][pix] 16*16384

// d_out used as partial scratch between k1 and k1r (k2 overwrites it fully):
// PS[g][b][lc][4096] = 16*4*15*4096 = 3,932,160 floats; PSS at +3,932,160.
#define PS_OFF(g,b,lc) (((((g)*4+(b))*15)+(lc))*4096)
#define PSS_BASE 3932160

// ---- k1: stats partials (blocks 0..959) + precompute (block 960) ----
__global__ void __launch_bounds__(256) k1(const float* __restrict__ Q,
                                          const float* __restrict__ Wk,
                                          const float* __restrict__ conv_w,
                                          const float* __restrict__ gn_w,
                                          const float* __restrict__ conv_b,
                                          const float* __restrict__ gn_b,
                                          const float* __restrict__ bk,
                                          const int* __restrict__ bpos,
                                          const unsigned char* __restrict__ pmask,
                                          const float* __restrict__ x,
                                          float* __restrict__ ws,
                                          float* __restrict__ pscratch) {
    int t = threadIdx.x;
    int bx = blockIdx.x;
    if (bx >= 960) {
        // ================= precompute block =================
        __shared__ float red[256];
        __shared__ float sc[16];
        __shared__ float qsv[256];
        __shared__ float rden[16];
        // stage A: qt[h][m]
        for (int i = t; i < 4096; i += 256) {
            int h = i >> 8, m = i & 255;
            float s = 0.f;
            #pragma unroll
            for (int d = 0; d < 4; ++d) s += Q[h*4+d] * Wk[(h*4+d)*256 + m];
            ws[WS_QT + h*256 + m] = s;
        }
        __syncthreads();
        // stage B: wt[h][c], u[c][h]   (conv_w is L2-resident after first touch)
        for (int i = t; i < 2048; i += 256) {
            int h = i >> 7, c = i & 127;
            const float* qt = ws + WS_QT + h*256;
            float s = 0.f;
            #pragma unroll 32
            for (int m = 0; m < 256; ++m) s += qt[m] * conv_w[m*128 + c];
            ws[WS_WT + h*128 + c] = s;
            ws[WS_U  + c*16  + h] = s * gn_w[c];
        }
        __syncthreads();
        // U[g][h] and qsv[h][p]
        {
            int h = t >> 4, g2 = t & 15;
            float s = 0.f;
            #pragma unroll
            for (int cc = 0; cc < 8; ++cc) s += ws[WS_U + (g2*8+cc)*16 + h];
            ws[WS_UU + g2*16 + h] = s;
            float q = 0.f;
            #pragma unroll
            for (int r = 0; r < 16; ++r) q += ws[WS_QT + h*256 + r*16 + g2];
            qsv[h*16 + g2] = q;
        }
        // wb[h] partials (parallel over 16 lanes per h)
        {
            int h = t >> 4, p = t & 15;
            float s = 0.f;
            #pragma unroll
            for (int i = 0; i < 8; ++i) { int c = p*8+i; s += ws[WS_WT + h*128 + c] * gn_b[c]; }
            red[t] = s;
        }
        __syncthreads();
        if (t < 16) { float wb = 0.f;
            #pragma unroll
            for (int p = 0; p < 16; ++p) wb += red[t*16+p];
            sc[t] = wb; }
        __syncthreads();
        // s0[h] partials
        {
            int h = t >> 4, p = t & 15;
            float s = 0.f;
            #pragma unroll
            for (int i = 0; i < 16; ++i) { int m = p*16+i; s += ws[WS_QT + h*256 + m] * conv_b[m]; }
            red[t] = s;
        }
        __syncthreads();
        if (t < 16) {
            float s0 = 0.f;
            #pragma unroll
            for (int p = 0; p < 16; ++p) s0 += red[t*16+p];
            #pragma unroll
            for (int d = 0; d < 4; ++d) s0 += Q[t*4+d] * bk[t*4+d];
            sc[t] += s0;
            rden[t] = powf(1000.0f, -((float)(t >> 1)) * 0.125f);
        }
        if (t < 120) ws[WS_FLAG + t] = pmask[t] ? 1.f : 0.f;
        __syncthreads();
        for (int idx = t; idx < 1920; idx += 256) {
            int h = idx / 120, r = idx - h*120;     // r = b*30+l
            float pos = (float)bpos[r];
            float pt = 0.f;
            #pragma unroll
            for (int p = 0; p < 16; ++p) {
                float tab = pos * rden[p];
                float v = (p & 1) ? cosf(tab) : sinf(tab);
                pt += v * qsv[h*16 + p];
            }
            ws[WS_P2 + r*16 + h] = pt + sc[h];
        }
        return;
    }
    // ================= stats path =================
    // block = (b, lc, g); 16 consecutive bx share (b,lc) -> machine reads x near-in-order.
    int b  = bx / 240;
    int rem = bx - b*240;
    int lc = rem >> 4;          // 0..14, covers l = 2*lc, 2*lc+1
    int g  = rem & 15;
    const float* xb = x + (((b*30 + lc*2)*128) + g*8)*4096 + t*4;
    float4 s0 = make_float4(0.f,0.f,0.f,0.f), s1 = s0, s2 = s0, s3 = s0;
    float4 q0 = s0, q1 = s0, q2 = s0, q3 = s0;
    #pragma unroll
    for (int l = 0; l < 2; ++l) {
        const float* xl = xb + l*128*4096;
        #pragma unroll 2
        for (int c = 0; c < 8; ++c) {
            const float* xc = xl + c*4096;
            float4 v0 = *(const float4*)(xc);
            float4 v1 = *(const float4*)(xc + 1024);
            float4 v2 = *(const float4*)(xc + 2048);
            float4 v3 = *(const float4*)(xc + 3072);
            s0.x += v0.x; s0.y += v0.y; s0.z += v0.z; s0.w += v0.w;
            q0.x += v0.x*v0.x; q0.y += v0.y*v0.y; q0.z += v0.z*v0.z; q0.w += v0.w*v0.w;
            s1.x += v1.x; s1.y += v1.y; s1.z += v1.z; s1.w += v1.w;
            q1.x += v1.x*v1.x; q1.y += v1.y*v1.y; q1.z += v1.z*v1.z; q1.w += v1.w*v1.w;
            s2.x += v2.x; s2.y += v2.y; s2.z += v2.z; s2.w += v2.w;
            q2.x += v2.x*v2.x; q2.y += v2.y*v2.y; q2.z += v2.z*v2.z; q2.w += v2.w*v2.w;
            s3.x += v3.x; s3.y += v3.y; s3.z += v3.z; s3.w += v3.w;
            q3.x += v3.x*v3.x; q3.y += v3.y*v3.y; q3.z += v3.z*v3.z; q3.w += v3.w*v3.w;
        }
    }
    float* ps  = pscratch + PS_OFF(g,b,lc) + t*4;
    float* pss = ps + PSS_BASE;
    *(float4*)(ps)        = s0;  *(float4*)(ps + 1024)  = s1;
    *(float4*)(ps + 2048) = s2;  *(float4*)(ps + 3072)  = s3;
    *(float4*)(pss)        = q0; *(float4*)(pss + 1024) = q1;
    *(float4*)(pss + 2048) = q2; *(float4*)(pss + 3072) = q3;
}

// ---- k1r: reduce 15 partials -> inv, mui ----
__global__ void __launch_bounds__(256) k1r(const float* __restrict__ pscratch,
                                           float* __restrict__ ws) {
    int idx = blockIdx.x*256 + threadIdx.x;   // 262144 = 16 g * 16384 pix
    int g = idx >> 14;
    int pix = idx & 16383;
    int b = pix >> 12, pij = pix & 4095;
    const float* ps  = pscratch + PS_OFF(g,b,0) + pij;
    const float* pss = ps + PSS_BASE;
    float S = 0.f, SS = 0.f;
    #pragma unroll
    for (int lc = 0; lc < 15; ++lc) {
        S  += ps[lc*4096];
        SS += pss[lc*4096];
    }
    float mu  = S * (1.f/240.f);
    float var = SS * (1.f/240.f) - mu*mu;
    float inv = rsqrtf(var + EPSV);
    ws[WS_INV + g*16384 + pix] = inv;
    ws[WS_MUI + g*16384 + pix] = mu * inv;
}

#define FMA4(A, S, V) { (A).x += (S)*(V).x; (A).y += (S)*(V).y; (A).z += (S)*(V).z; (A).w += (S)*(V).w; }
#define NMA4(A, S, V) { (A).x -= (S)*(V).x; (A).y -= (S)*(V).y; (A).z -= (S)*(V).z; (A).w -= (S)*(V).w; }

// ---- k2: raw scores, 4 pixels/thread ----
__global__ void __launch_bounds__(256) k2(const float* __restrict__ x,
                                          const float* __restrict__ ws,
                                          float* __restrict__ out) {
    __shared__ float su[2048];   // u[c][h]
    __shared__ float sU[256];    // U[g][h]
    __shared__ float sP2[16];
    __shared__ float sflag;
    int t = threadIdx.x;
    int bx = blockIdx.x;                 // 480 blocks: pb2 = bx/30, l = bx%30
    int pb2 = bx / 30, l = bx - pb2*30;
    int pixbase = pb2 * 1024;            // block-uniform
    int b = pixbase >> 12;
    int pijb = pixbase & 4095;
    int bl = b*30 + l;
    int pij = pijb + t*4;
    int pix0 = pixbase + t*4;

    for (int i = t; i < 512; i += 256)
        *(float4*)(su + i*4) = *(const float4*)(ws + WS_U + i*4);
    sU[t] = ws[WS_UU + t];
    if (t < 16) sP2[t] = ws[WS_P2 + bl*16 + t];
    if (t == 0) sflag = ws[WS_FLAG + bl];
    __syncthreads();

    float4 acc[16];
    #pragma unroll
    for (int h = 0; h < 16; ++h) acc[h] = make_float4(0.f, 0.f, 0.f, 0.f);
    const float* xbase = x + (bl*128)*4096 + pij;
    #pragma unroll 2
    for (int g = 0; g < 16; ++g) {
        float4 inv = *(const float4*)(ws + WS_INV + g*16384 + pix0);
        float4 mui = *(const float4*)(ws + WS_MUI + g*16384 + pix0);
        const float* us = su + g*128;
        #pragma unroll
        for (int q = 0; q < 4; ++q) {
            float4 Ug = *(const float4*)(sU + g*16 + q*4);
            NMA4(acc[q*4+0], Ug.x, mui); NMA4(acc[q*4+1], Ug.y, mui);
            NMA4(acc[q*4+2], Ug.z, mui); NMA4(acc[q*4+3], Ug.w, mui);
        }
        const float* xg = xbase + g*8*4096;
        #pragma unroll
        for (int cc = 0; cc < 8; ++cc) {
            float4 v = *(const float4*)(xg + cc*4096);
            float4 xs;
            xs.x = v.x*inv.x; xs.y = v.y*inv.y; xs.z = v.z*inv.z; xs.w = v.w*inv.w;
            #pragma unroll
            for (int q = 0; q < 4; ++q) {
                float4 uq = *(const float4*)(us + cc*16 + q*4);  // ds_read_b128 broadcast
                FMA4(acc[q*4+0], uq.x, xs); FMA4(acc[q*4+1], uq.y, xs);
                FMA4(acc[q*4+2], uq.z, xs); FMA4(acc[q*4+3], uq.w, xs);
            }
        }
    }
    bool msk = (sflag != 0.f);
    #pragma unroll
    for (int h = 0; h < 16; ++h) {
        float p2 = sP2[h];
        float4 sv;
        sv.x = 0.5f*(acc[h].x + p2); sv.y = 0.5f*(acc[h].y + p2);
        sv.z = 0.5f*(acc[h].z + p2); sv.w = 0.5f*(acc[h].w + p2);
        if (msk) sv = make_float4(-1000.f, -1000.f, -1000.f, -1000.f);
        *(float4*)(out + ((h*4 + b)*30 + l)*4096 + pij) = sv;
    }
}

// ---- k3: softmax over l, 2 pixels/thread ----
__global__ void __launch_bounds__(256) k3(float* __restrict__ out) {
    int idx = blockIdx.x*256 + threadIdx.x;   // 131072 threads
    int hb = idx >> 11;                       // 64 (h*4+b) slabs
    int pij = (idx & 2047)*2;
    float* p = out + hb*30*4096 + pij;
    float2 v[30];
    float m0 = -1e30f, m1 = -1e30f;
    #pragma unroll
    for (int l = 0; l < 30; ++l) {
        v[l] = *(const float2*)(p + l*4096);
        m0 = fmaxf(m0, v[l].x); m1 = fmaxf(m1, v[l].y);
    }
    float s0 = 0.f, s1 = 0.f;
    #pragma unroll
    for (int l = 0; l < 30; ++l) {
        v[l].x = __expf(v[l].x - m0); s0 += v[l].x;
        v[l].y = __expf(v[l].y - m1); s1 += v[l].y;
    }
    float r0 = 1.f/s0, r1 = 1.f/s1;
    #pragma unroll
    for (int l = 0; l < 30; ++l) {
        *(float2*)(p + l*4096) = make_float2(v[l].x*r0, v[l].y*r1);
    }
}

extern "C" void kernel_launch(void* const* d_in, const int* in_sizes, int n_in,
                              void* d_out, int out_size, void* d_ws, size_t ws_size,
                              hipStream_t stream) {
    const float* x      = (const float*)d_in[0];
    const float* gn_w   = (const float*)d_in[1];
    const float* gn_b   = (const float*)d_in[2];
    const float* conv_w = (const float*)d_in[3];
    const float* conv_b = (const float*)d_in[4];
    const float* Q      = (const float*)d_in[5];
    const float* Wk     = (const float*)d_in[6];
    const float* bk     = (const float*)d_in[7];
    const int*   bpos   = (const int*)d_in[8];
    const unsigned char* pmask = (const unsigned char*)d_in[9];
    float* ws  = (float*)d_ws;
    float* out = (float*)d_out;

    hipLaunchKernelGGL(k1,  dim3(961),  dim3(256), 0, stream,
                       Q, Wk, conv_w, gn_w, conv_b, gn_b, bk, bpos, pmask, x, ws, out);
    hipLaunchKernelGGL(k1r, dim3(1024), dim3(256), 0, stream, out, ws);
    hipLaunchKernelGGL(k2,  dim3(480),  dim3(256), 0, stream, x, ws, out);
    hipLaunchKernelGGL(k3,  dim3(512),  dim3(256), 0, stream, out);
}